// Round 6
// baseline (240.574 us; speedup 1.0000x reference)
//
#include <hip/hip_runtime.h>

// Problem constants (from reference setup_inputs)
constexpr int B = 4, D = 32, C = 3, H = 256, W = 384;
constexpr int HW  = H * W;           // 98304
constexpr int HW4 = HW / 4;          // 24576 float4-groups per plane-image
constexpr int NGRP = B * HW4;        // 98304 float4 groups total
constexpr int TILE = 64;             // float4-groups per block (one wave wide)
constexpr int NBLK = NGRP / TILE;    // 1536 blocks
constexpr int SEGS = 4;              // D-segments == waves per block
constexpr int DSEG = D / SEGS;       // 8 planes per segment

// Per-pixel segment state: T = prod(1-a) over segment, V = sum(vis),
// Acc_c = sum(s_c * vis) with vis computed with segment-local exclusive
// cumprod. Compose(front X, back Y): Acc = X.Acc + X.T*Y.Acc;
// V = X.V + X.T*Y.V; T = X.T*Y.T.  (associative)

__global__ __launch_bounds__(256)
void alpha_comp_kernel(const float* __restrict__ src,
                       const float* __restrict__ alpha,
                       float* __restrict__ out)
{
    // States for segments 1..3 (wave 0 keeps its own in registers)
    __shared__ float4 stT[SEGS - 1][TILE];
    __shared__ float4 stV[SEGS - 1][TILE];
    __shared__ float4 stA[3][SEGS - 1][TILE];

    const int t = threadIdx.x;
    const int w = t >> 6;                    // wave id == D-segment id
    const int l = t & 63;                    // lane
    const int g = blockIdx.x * TILE + l;     // float4-group index (global)
    const int b   = g / HW4;                 // HW4 % TILE == 0, no straddle
    const int hw4 = g - b * HW4;

    const float4* __restrict__ ap =
        reinterpret_cast<const float4*>(alpha) + (size_t)b * D * HW4 + hw4;
    const float4* __restrict__ sp =
        reinterpret_cast<const float4*>(src) + (size_t)b * D * C * HW4 + hw4;

    float res[4]    = {1.f, 1.f, 1.f, 1.f};
    float vsum[4]   = {0.f, 0.f, 0.f, 0.f};
    float acc[3][4] = {};

    const int d0 = w * DSEG;
    #pragma unroll
    for (int i = 0; i < DSEG; ++i) {
        const int d = d0 + i;
        const float4 a  = ap[(size_t)d * HW4];
        const float4 s0 = sp[((size_t)d * C + 0) * HW4];
        const float4 s1 = sp[((size_t)d * C + 1) * HW4];
        const float4 s2 = sp[((size_t)d * C + 2) * HW4];

        const float av[4]  = {a.x, a.y, a.z, a.w};
        const float s0v[4] = {s0.x, s0.y, s0.z, s0.w};
        const float s1v[4] = {s1.x, s1.y, s1.z, s1.w};
        const float s2v[4] = {s2.x, s2.y, s2.z, s2.w};

        #pragma unroll
        for (int k = 0; k < 4; ++k) {
            const float vis = res[k] * av[k];
            vsum[k]  += vis;
            acc[0][k] = fmaf(s0v[k], vis, acc[0][k]);
            acc[1][k] = fmaf(s1v[k], vis, acc[1][k]);
            acc[2][k] = fmaf(s2v[k], vis, acc[2][k]);
            res[k]   *= (1.f - av[k]);
        }
    }

    if (w > 0) {
        stT[w - 1][l] = make_float4(res[0], res[1], res[2], res[3]);
        stV[w - 1][l] = make_float4(vsum[0], vsum[1], vsum[2], vsum[3]);
        #pragma unroll
        for (int c = 0; c < 3; ++c)
            stA[c][w - 1][l] =
                make_float4(acc[c][0], acc[c][1], acc[c][2], acc[c][3]);
    }
    __syncthreads();

    if (w == 0) {
        // Fold segments 1..3 onto wave 0's register state (front-to-back).
        #pragma unroll
        for (int s = 1; s < SEGS; ++s) {
            const float4 T2 = stT[s - 1][l];
            const float4 V2 = stV[s - 1][l];
            const float4 A2_0 = stA[0][s - 1][l];
            const float4 A2_1 = stA[1][s - 1][l];
            const float4 A2_2 = stA[2][s - 1][l];
            const float* t2 = &T2.x;
            const float* v2 = &V2.x;
            const float* a2[3] = {&A2_0.x, &A2_1.x, &A2_2.x};
            #pragma unroll
            for (int k = 0; k < 4; ++k) {
                vsum[k]   = fmaf(res[k], v2[k], vsum[k]);
                acc[0][k] = fmaf(res[k], a2[0][k], acc[0][k]);
                acc[1][k] = fmaf(res[k], a2[1][k], acc[1][k]);
                acc[2][k] = fmaf(res[k], a2[2][k], acc[2][k]);
                res[k]   *= t2[k];
            }
        }

        float inv[4];
        #pragma unroll
        for (int k = 0; k < 4; ++k)
            inv[k] = 1.f / fmaxf(vsum[k], 1e-7f);

        float4* __restrict__ op =
            reinterpret_cast<float4*>(out) + (size_t)b * C * HW4 + hw4;
        #pragma unroll
        for (int c = 0; c < C; ++c) {
            float4 o;
            o.x = acc[c][0] * inv[0];
            o.y = acc[c][1] * inv[1];
            o.z = acc[c][2] * inv[2];
            o.w = acc[c][3] * inv[3];
            op[(size_t)c * HW4] = o;
        }
    }
}

extern "C" void kernel_launch(void* const* d_in, const int* in_sizes, int n_in,
                              void* d_out, int out_size, void* d_ws, size_t ws_size,
                              hipStream_t stream)
{
    const float* src   = (const float*)d_in[0];   // [B, D, C, H, W]
    const float* alpha = (const float*)d_in[1];   // [B, D, 1, H, W]
    float* out = (float*)d_out;                   // [B, C, H, W]

    alpha_comp_kernel<<<NBLK, 256, 0, stream>>>(src, alpha, out);
}